// Round 6
// baseline (2878.264 us; speedup 1.0000x reference)
//
#include <hip/hip_runtime.h>
#include <stdint.h>

#define H 512
#define B_SZ 1024
#define T_WARM 256
#define NSTEPS 64
#define TOTAL_T (T_WARM + NSTEPS)

#define RPB 32          // rows per team
#define HC 64           // cols per block
#define NTEAM 32        // B_SZ / RPB
#define NCG 8           // H / HC
#define NBLK 256        // NTEAM * NCG == CU count, 1 block/CU
#define NTHR 512        // 8 waves
#define HSTR 520        // padded LDS k-stride (ushorts)

typedef __attribute__((ext_vector_type(8))) short bf16x8;
typedef __attribute__((ext_vector_type(4))) float f32x4;

__device__ __forceinline__ ushort f2bf(float f) {
    uint32_t u = __builtin_bit_cast(uint32_t, f);
    u += 0x7FFFu + ((u >> 16) & 1u);
    return (ushort)(u >> 16);
}
__device__ __forceinline__ float bf2f(ushort h) {
    uint32_t u = ((uint32_t)h) << 16;
    return __builtin_bit_cast(float, u);
}

__global__ void prep_kernel(const float* __restrict__ x,
                            const float* __restrict__ W_hh,
                            const float* __restrict__ b_ih,
                            const float* __restrict__ b_hh,
                            ushort* __restrict__ Wh, ushort* __restrict__ Wl,
                            float* __restrict__ bias, float* __restrict__ xT,
                            uint32_t* __restrict__ Hb0, uint32_t* __restrict__ flags) {
    int i = blockIdx.x * NTHR + threadIdx.x;     // [0, 524288)
    Hb0[i] = 0u;                                  // h(0) = 0
    if (i < 4096) flags[i] = 0u;                  // flag region (16 KB)
    if (i < H * H) {
        float w = W_hh[i];
        ushort hi = f2bf(w);
        float rem = w - bf2f(hi);
        Wh[i] = hi;
        Wl[i] = f2bf(rem);
    }
    if (i < B_SZ * T_WARM) {
        int b = i & (B_SZ - 1), t = i >> 10;
        xT[t * B_SZ + b] = x[b * T_WARM + t];
    }
    if (i < H) bias[i] = b_ih[i] + b_hh[i];
}

__global__ __launch_bounds__(NTHR, 1)
void rnn_kernel(const float* __restrict__ xT,
                const float* __restrict__ W_ih,
                const float* __restrict__ b_fc_p,
                const float* __restrict__ W_fc,
                const ushort* __restrict__ Wh_g,
                const ushort* __restrict__ Wl_g,
                const float* __restrict__ bias_g,
                uint32_t* __restrict__ Hb0, uint32_t* __restrict__ Hb1,
                uint32_t* __restrict__ flags,
                float* __restrict__ out) {
    __shared__ ushort h_hi[RPB * HSTR];    // 33280 B
    __shared__ ushort h_lo[RPB * HSTR];    // 33280 B
    __shared__ float w_fc_s[H];
    __shared__ float w_in_s[HC];
    __shared__ float bias_s[HC];
    __shared__ float sx[RPB];
    __shared__ float sy[RPB];

    const int tid = threadIdx.x;
    const int bid = blockIdx.x;
    const int team = bid & (NTEAM - 1);    // team blocks share XCD residue (perf heuristic only)
    const int cg = bid >> 5;
    const int row0 = team * RPB;
    const int col0 = cg * HC;

    w_fc_s[tid & (H - 1)] = W_fc[tid & (H - 1)];
    if (tid < HC) { w_in_s[tid] = W_ih[col0 + tid]; bias_s[tid] = bias_g[col0 + tid]; }
    const float bfc = b_fc_p[0];

    const int lane = tid & 63;
    const int wv = tid >> 6;
    const int n = lane & 15, q = lane >> 4;
    const int r2 = wv >> 2, c4 = wv & 3;   // wave tile: rows r2*16, cols c4*16

    // ---- weights register-resident for all 320 steps: 128 VGPRs ----
    bf16x8 Bh[16], Bl[16];
    {
        const ushort* wh = Wh_g + (col0 + c4 * 16 + n) * H + q * 8;
        const ushort* wl = Wl_g + (col0 + c4 * 16 + n) * H + q * 8;
        #pragma unroll
        for (int kt = 0; kt < 16; ++kt) {
            Bh[kt] = *(const bf16x8*)(wh + kt * 32);
            Bl[kt] = *(const bf16x8*)(wl + kt * 32);
        }
    }

    // per-wave flags: producer block (team,cg), wave w -> flags[(team*8+cg)*8 + w]
    uint32_t* myflag = flags + (team * NCG + cg) * 8 + wv;
    const uint64_t* pollbase = (const uint64_t*)(flags + (team * NCG + wv) * 8);

    for (int t = 0; t < TOTAL_T; ++t) {
        // x for this step -> register, issued before any waiting
        float xv = 0.f;
        if (t < T_WARM && tid < RPB) xv = xT[t * B_SZ + row0 + tid];

        // ---- wave wv waits for ALL 8 waves of producer block (team, wv) ----
        if (t > 0) {
            const uint32_t tt = (uint32_t)t;
            for (;;) {
                uint64_t f0 = __hip_atomic_load(pollbase + 0, __ATOMIC_RELAXED, __HIP_MEMORY_SCOPE_AGENT);
                uint64_t f1 = __hip_atomic_load(pollbase + 1, __ATOMIC_RELAXED, __HIP_MEMORY_SCOPE_AGENT);
                uint64_t f2 = __hip_atomic_load(pollbase + 2, __ATOMIC_RELAXED, __HIP_MEMORY_SCOPE_AGENT);
                uint64_t f3 = __hip_atomic_load(pollbase + 3, __ATOMIC_RELAXED, __HIP_MEMORY_SCOPE_AGENT);
                uint32_t m0 = min((uint32_t)f0, (uint32_t)(f0 >> 32));
                uint32_t m1 = min((uint32_t)f1, (uint32_t)(f1 >> 32));
                uint32_t m2 = min((uint32_t)f2, (uint32_t)(f2 >> 32));
                uint32_t m3 = min((uint32_t)f3, (uint32_t)(f3 >> 32));
                if (min(min(m0, m1), min(m2, m3)) >= tt) break;
                __builtin_amdgcn_s_sleep(1);
            }
        }

        // ---- phase 1: batched loads of OWN slice only (k-cols [wv*64, wv*64+64)) ----
        // RACE FIX vs r5: wave wv touches only the slice whose producer it polled.
        uint64_t tmp[16];
        {
            const uint32_t* hb = (t & 1) ? Hb1 : Hb0;
            const uint64_t* src = (const uint64_t*)hb;
            #pragma unroll
            for (int it = 0; it < 16; ++it) {
                int flat = it * 64 + lane;         // [0,1024): r = flat>>5, cpair = flat&31
                int r = flat >> 5, cpair = flat & 31;
                tmp[it] = __hip_atomic_load(src + ((row0 + r) * 256 + wv * 32 + cpair),
                                            __ATOMIC_RELAXED, __HIP_MEMORY_SCOPE_AGENT);
            }
        }
        // WAR barrier (prior step's LDS reads done); its vmcnt(0) drain doubles as load wait
        __syncthreads();

        // ---- phase 2: unpack + LDS fill (own slice) ----
        #pragma unroll
        for (int it = 0; it < 16; ++it) {
            int flat = it * 64 + lane;
            int r = flat >> 5, cpair = flat & 31;
            int k = wv * 64 + cpair * 2;
            uint64_t u = tmp[it];
            uint32_t w0 = (uint32_t)u, w1 = (uint32_t)(u >> 32);
            uint32_t hw = (w0 >> 16) | (w1 & 0xFFFF0000u);
            uint32_t lw = (w0 & 0xFFFFu) | (w1 << 16);
            *(uint32_t*)(&h_hi[r * HSTR + k]) = hw;
            *(uint32_t*)(&h_lo[r * HSTR + k]) = lw;
        }
        if (t < T_WARM && tid < RPB) sx[tid] = xv;
        __syncthreads();

        // ---- rollout: y = h . w_fc + b_fc (redundant per cg; cg0 writes out) ----
        if (t >= T_WARM) {
            int r = tid >> 4, seg = tid & 15;
            const ushort* hh = &h_hi[r * HSTR];
            const ushort* hl = &h_lo[r * HSTR];
            float s = 0.f;
            #pragma unroll
            for (int kk = 0; kk < 32; ++kk) {
                int k = seg + kk * 16;
                s += (bf2f(hh[k]) + bf2f(hl[k])) * w_fc_s[k];
            }
            #pragma unroll
            for (int off = 8; off; off >>= 1) s += __shfl_down(s, off, 16);
            if (seg == 0) {
                float y = s + bfc;
                sy[r] = y;
                if (cg == 0) out[(row0 + r) * NSTEPS + (t - T_WARM)] = y;
            }
            __syncthreads();
        }

        // ---- MFMA: 16 k-tiles x (2 ds_read_b128 + 3 MFMA), B in registers ----
        f32x4 acc0 = {0.f, 0.f, 0.f, 0.f}, acc1 = {0.f, 0.f, 0.f, 0.f};
        const ushort* ha = &h_hi[(r2 * 16 + n) * HSTR] + q * 8;
        const ushort* la = &h_lo[(r2 * 16 + n) * HSTR] + q * 8;
        #pragma unroll
        for (int kt = 0; kt < 16; kt += 2) {
            {
                bf16x8 ah = *(const bf16x8*)(ha + kt * 32);
                bf16x8 al = *(const bf16x8*)(la + kt * 32);
                acc0 = __builtin_amdgcn_mfma_f32_16x16x32_bf16(ah, Bh[kt], acc0, 0, 0, 0);
                acc0 = __builtin_amdgcn_mfma_f32_16x16x32_bf16(al, Bh[kt], acc0, 0, 0, 0);
                acc0 = __builtin_amdgcn_mfma_f32_16x16x32_bf16(ah, Bl[kt], acc0, 0, 0, 0);
            }
            {
                bf16x8 ah = *(const bf16x8*)(ha + (kt + 1) * 32);
                bf16x8 al = *(const bf16x8*)(la + (kt + 1) * 32);
                acc1 = __builtin_amdgcn_mfma_f32_16x16x32_bf16(ah, Bh[kt + 1], acc1, 0, 0, 0);
                acc1 = __builtin_amdgcn_mfma_f32_16x16x32_bf16(al, Bh[kt + 1], acc1, 0, 0, 0);
                acc1 = __builtin_amdgcn_mfma_f32_16x16x32_bf16(ah, Bl[kt + 1], acc1, 0, 0, 0);
            }
        }

        // ---- epilogue: v = acc + s*w_in + bias, relu, pack hi|lo, publish ----
        const int jl = c4 * 16 + n;
        const float wi = w_in_s[jl], bj = bias_s[jl];
        uint32_t* dst = ((t & 1) ? Hb0 : Hb1) + col0 + jl;
        #pragma unroll
        for (int i = 0; i < 4; ++i) {
            int m = r2 * 16 + q * 4 + i;           // C/D: row = quad*4+reg, col = lane&15
            float sv = (t < T_WARM) ? sx[m] : sy[m];
            float v = acc0[i] + acc1[i] + sv * wi + bj;
            v = fmaxf(v, 0.f);
            ushort hi = f2bf(v);
            float rem = v - bf2f(hi);
            uint32_t u = ((uint32_t)hi << 16) | (uint32_t)f2bf(rem);
            __hip_atomic_store(dst + (row0 + m) * H, u, __ATOMIC_RELAXED, __HIP_MEMORY_SCOPE_AGENT);
        }
        // per-wave drain of own stores, then publish own flag.
        // sched_barrier(0) pins ordering: stores -> waitcnt -> flag store.
        __builtin_amdgcn_sched_barrier(0);
        __builtin_amdgcn_s_waitcnt(0x0f70);   // vmcnt(0), expcnt/lgkmcnt unaffected
        __builtin_amdgcn_sched_barrier(0);
        if (lane == 0)
            __hip_atomic_store(myflag, (uint32_t)(t + 1), __ATOMIC_RELAXED, __HIP_MEMORY_SCOPE_AGENT);
        __builtin_amdgcn_sched_barrier(0);
    }
}

extern "C" void kernel_launch(void* const* d_in, const int* in_sizes, int n_in,
                              void* d_out, int out_size, void* d_ws, size_t ws_size,
                              hipStream_t stream) {
    const float* x    = (const float*)d_in[0];
    const float* W_ih = (const float*)d_in[1];
    const float* W_hh = (const float*)d_in[2];
    const float* b_ih = (const float*)d_in[3];
    const float* b_hh = (const float*)d_in[4];
    const float* W_fc = (const float*)d_in[5];
    const float* b_fc = (const float*)d_in[6];
    float* out = (float*)d_out;

    // ws carve (bytes): Wh 512K | Wl 512K | bias 4K | xT 1M | Hb0 2M | Hb1 2M | flags 16K
    uint8_t* w = (uint8_t*)d_ws;
    ushort*   Wh    = (ushort*)(w);
    ushort*   Wl    = (ushort*)(w + 524288);
    float*    bias  = (float*)(w + 1048576);
    float*    xT    = (float*)(w + 1052672);
    uint32_t* Hb0   = (uint32_t*)(w + 2101248);
    uint32_t* Hb1   = (uint32_t*)(w + 4198400);
    uint32_t* flags = (uint32_t*)(w + 6295552);

    prep_kernel<<<1024, NTHR, 0, stream>>>(x, W_hh, b_ih, b_hh, Wh, Wl, bias, xT, Hb0, flags);
    rnn_kernel<<<NBLK, NTHR, 0, stream>>>(xT, W_ih, b_fc, W_fc, Wh, Wl, bias, Hb0, Hb1, flags, out);
}

// Round 7
// 1030.372 us; speedup vs baseline: 2.7934x; 2.7934x over previous
//
#include <hip/hip_runtime.h>
#include <stdint.h>

#define H 512
#define B_SZ 1024
#define T_WARM 256
#define NSTEPS 64
#define TOTAL_T (T_WARM + NSTEPS)

#define RPB 16          // rows per team
#define HC 128          // cols per block
#define NTEAM 64        // B_SZ / RPB
#define NCG 4           // H / HC
#define NBLK 256        // NTEAM * NCG == CU count, 1 block/CU
#define NTHR 512        // 8 waves
#define HSTR 520        // padded LDS k-stride (ushorts)

typedef __attribute__((ext_vector_type(8))) short bf16x8;
typedef __attribute__((ext_vector_type(4))) float f32x4;

__device__ __forceinline__ ushort f2bf(float f) {
    uint32_t u = __builtin_bit_cast(uint32_t, f);
    u += 0x7FFFu + ((u >> 16) & 1u);
    return (ushort)(u >> 16);
}
__device__ __forceinline__ float bf2f(ushort h) {
    uint32_t u = ((uint32_t)h) << 16;
    return __builtin_bit_cast(float, u);
}

__global__ void prep_kernel(const float* __restrict__ x,
                            const float* __restrict__ W_hh,
                            const float* __restrict__ b_ih,
                            const float* __restrict__ b_hh,
                            ushort* __restrict__ Wh, ushort* __restrict__ Wl,
                            float* __restrict__ bias, float* __restrict__ xT,
                            uint32_t* __restrict__ Hb0, uint32_t* __restrict__ flags) {
    int i = blockIdx.x * NTHR + threadIdx.x;     // [0, 524288)
    Hb0[i] = 0u;                                  // h(0) = 0
    if (i < 4096) flags[i] = 0u;                  // flag region (16 KB)
    if (i < H * H) {
        float w = W_hh[i];
        ushort hi = f2bf(w);
        float rem = w - bf2f(hi);
        Wh[i] = hi;
        Wl[i] = f2bf(rem);
    }
    if (i < B_SZ * T_WARM) {
        int b = i & (B_SZ - 1), t = i >> 10;
        xT[t * B_SZ + b] = x[b * T_WARM + t];
    }
    if (i < H) bias[i] = b_ih[i] + b_hh[i];
}

__global__ __launch_bounds__(NTHR, 1)
void rnn_kernel(const float* __restrict__ xT,
                const float* __restrict__ W_ih,
                const float* __restrict__ b_fc_p,
                const float* __restrict__ W_fc,
                const ushort* __restrict__ Wh_g,
                const ushort* __restrict__ Wl_g,
                const float* __restrict__ bias_g,
                uint32_t* __restrict__ Hb0, uint32_t* __restrict__ Hb1,
                uint32_t* __restrict__ flags,
                float* __restrict__ out) {
    __shared__ ushort h_hi[RPB * HSTR];    // 16640 B
    __shared__ ushort h_lo[RPB * HSTR];    // 16640 B
    __shared__ float w_fc_s[H];
    __shared__ float w_in_s[HC];
    __shared__ float bias_s[HC];
    __shared__ float sx[RPB];
    __shared__ float sy[RPB];

    const int tid = threadIdx.x;
    const int bid = blockIdx.x;
    const int team = bid & (NTEAM - 1);    // blocks {team, +64, +128, +192} share bid%8 (XCD)
    const int cg = bid >> 6;               // 0..3
    const int row0 = team * RPB;
    const int col0 = cg * HC;

    w_fc_s[tid & (H - 1)] = W_fc[tid & (H - 1)];
    if (tid < HC) { w_in_s[tid] = W_ih[col0 + tid]; bias_s[tid] = bias_g[col0 + tid]; }
    const float bfc = b_fc_p[0];

    const int lane = tid & 63;
    const int wv = tid >> 6;               // 0..7 = col-tile within block
    const int n = lane & 15, q = lane >> 4;

    // ---- weights register-resident for all 320 steps: 128 regs/thread ----
    // wave wv owns cols [col0 + wv*16, +16), full K=512
    bf16x8 Bh[16], Bl[16];
    {
        const ushort* wh = Wh_g + (col0 + wv * 16 + n) * H + q * 8;
        const ushort* wl = Wl_g + (col0 + wv * 16 + n) * H + q * 8;
        #pragma unroll
        for (int kt = 0; kt < 16; ++kt) {
            Bh[kt] = *(const bf16x8*)(wh + kt * 32);
            Bl[kt] = *(const bf16x8*)(wl + kt * 32);
        }
    }

    // block flag: producer (team, cg) -> flags[(team*4+cg)*16], 64B stride
    uint32_t* myflag = flags + (team * NCG + cg) * 16;
    // wave wv stages k-slice [wv*64, +64), produced by block (team, wv>>1)
    const uint32_t* pollflag = flags + (team * NCG + (wv >> 1)) * 16;

    for (int t = 0; t < TOTAL_T; ++t) {
        // x for this step -> register, issued before any waiting
        float xv = 0.f;
        if (t < T_WARM && tid < RPB) xv = xT[t * B_SZ + row0 + tid];

        // ---- wave wv waits for its producer block's flag (single word, relaxed) ----
        if (t > 0) {
            while (__hip_atomic_load(pollflag, __ATOMIC_RELAXED, __HIP_MEMORY_SCOPE_AGENT)
                   < (uint32_t)t)
                __builtin_amdgcn_s_sleep(1);
        }

        // ---- phase 1: batched loads of own k-slice [wv*64, +64) x 16 rows ----
        uint64_t tmp[8];
        {
            const uint32_t* hb = (t & 1) ? Hb1 : Hb0;
            const uint64_t* src = (const uint64_t*)hb;
            #pragma unroll
            for (int it = 0; it < 8; ++it) {
                int idx = it * 64 + lane;          // [0,512): r = idx>>5, cpair = idx&31
                int r = idx >> 5, cpair = idx & 31;
                tmp[it] = __hip_atomic_load(src + ((row0 + r) * 256 + wv * 32 + cpair),
                                            __ATOMIC_RELAXED, __HIP_MEMORY_SCOPE_AGENT);
            }
        }
        // WAR barrier (prior step's LDS reads done); also drains phase-1 loads (vmcnt0)
        __syncthreads();

        // ---- phase 2: unpack + LDS fill (own slice) ----
        #pragma unroll
        for (int it = 0; it < 8; ++it) {
            int idx = it * 64 + lane;
            int r = idx >> 5, cpair = idx & 31;
            int k = wv * 64 + cpair * 2;
            uint64_t u = tmp[it];
            uint32_t w0 = (uint32_t)u, w1 = (uint32_t)(u >> 32);
            uint32_t hw = (w0 >> 16) | (w1 & 0xFFFF0000u);
            uint32_t lw = (w0 & 0xFFFFu) | (w1 << 16);
            *(uint32_t*)(&h_hi[r * HSTR + k]) = hw;
            *(uint32_t*)(&h_lo[r * HSTR + k]) = lw;
        }
        if (t < T_WARM && tid < RPB) sx[tid] = xv;
        __syncthreads();

        // ---- rollout: y = h . w_fc + b_fc (redundant per cg; cg0 writes out) ----
        if (t >= T_WARM) {
            if (tid < RPB * 16) {
                int r = tid >> 4, seg = tid & 15;
                const ushort* hh = &h_hi[r * HSTR];
                const ushort* hl = &h_lo[r * HSTR];
                float s = 0.f;
                #pragma unroll
                for (int kk = 0; kk < 32; ++kk) {
                    int k = seg + kk * 16;
                    s += (bf2f(hh[k]) + bf2f(hl[k])) * w_fc_s[k];
                }
                #pragma unroll
                for (int off = 8; off; off >>= 1) s += __shfl_down(s, off, 16);
                if (seg == 0) {
                    float y = s + bfc;
                    sy[r] = y;
                    if (cg == 0) out[(row0 + r) * NSTEPS + (t - T_WARM)] = y;
                }
            }
            __syncthreads();
        }

        // ---- MFMA: A(16 rows x 512) @ B(512 x 16 cols), 16 kt x 3 terms ----
        f32x4 acc0 = {0.f, 0.f, 0.f, 0.f}, acc1 = {0.f, 0.f, 0.f, 0.f};
        const ushort* ha = &h_hi[n * HSTR] + q * 8;    // A row = n
        const ushort* la = &h_lo[n * HSTR] + q * 8;
        #pragma unroll
        for (int kt = 0; kt < 16; kt += 2) {
            {
                bf16x8 ah = *(const bf16x8*)(ha + kt * 32);
                bf16x8 al = *(const bf16x8*)(la + kt * 32);
                acc0 = __builtin_amdgcn_mfma_f32_16x16x32_bf16(ah, Bh[kt], acc0, 0, 0, 0);
                acc0 = __builtin_amdgcn_mfma_f32_16x16x32_bf16(al, Bh[kt], acc0, 0, 0, 0);
                acc0 = __builtin_amdgcn_mfma_f32_16x16x32_bf16(ah, Bl[kt], acc0, 0, 0, 0);
            }
            {
                bf16x8 ah = *(const bf16x8*)(ha + (kt + 1) * 32);
                bf16x8 al = *(const bf16x8*)(la + (kt + 1) * 32);
                acc1 = __builtin_amdgcn_mfma_f32_16x16x32_bf16(ah, Bh[kt + 1], acc1, 0, 0, 0);
                acc1 = __builtin_amdgcn_mfma_f32_16x16x32_bf16(al, Bh[kt + 1], acc1, 0, 0, 0);
                acc1 = __builtin_amdgcn_mfma_f32_16x16x32_bf16(ah, Bl[kt + 1], acc1, 0, 0, 0);
            }
        }

        // ---- epilogue: v = acc + s*w_in + bias, relu, pack hi|lo, publish ----
        const int jl = wv * 16 + n;                    // col within block
        const float wi = w_in_s[jl], bj = bias_s[jl];
        uint32_t* dst = ((t & 1) ? Hb0 : Hb1) + col0 + jl;
        #pragma unroll
        for (int i = 0; i < 4; ++i) {
            int m = q * 4 + i;                         // C/D: row = quad*4+reg, col = lane&15
            float sv = (t < T_WARM) ? sx[m] : sy[m];
            float v = acc0[i] + acc1[i] + sv * wi + bj;
            v = fmaxf(v, 0.f);
            ushort hi = f2bf(v);
            float rem = v - bf2f(hi);
            uint32_t u = ((uint32_t)hi << 16) | (uint32_t)f2bf(rem);
            __hip_atomic_store(dst + (row0 + m) * H, u, __ATOMIC_RELAXED, __HIP_MEMORY_SCOPE_AGENT);
        }
        __syncthreads();   // drains all waves' vmem (vmcnt0) before flag publish
        if (tid == 0)
            __hip_atomic_store(myflag, (uint32_t)(t + 1), __ATOMIC_RELAXED, __HIP_MEMORY_SCOPE_AGENT);
    }
}

extern "C" void kernel_launch(void* const* d_in, const int* in_sizes, int n_in,
                              void* d_out, int out_size, void* d_ws, size_t ws_size,
                              hipStream_t stream) {
    const float* x    = (const float*)d_in[0];
    const float* W_ih = (const float*)d_in[1];
    const float* W_hh = (const float*)d_in[2];
    const float* b_ih = (const float*)d_in[3];
    const float* b_hh = (const float*)d_in[4];
    const float* W_fc = (const float*)d_in[5];
    const float* b_fc = (const float*)d_in[6];
    float* out = (float*)d_out;

    // ws carve (bytes): Wh 512K | Wl 512K | bias 4K | xT 1M | Hb0 2M | Hb1 2M | flags 16K
    uint8_t* w = (uint8_t*)d_ws;
    ushort*   Wh    = (ushort*)(w);
    ushort*   Wl    = (ushort*)(w + 524288);
    float*    bias  = (float*)(w + 1048576);
    float*    xT    = (float*)(w + 1052672);
    uint32_t* Hb0   = (uint32_t*)(w + 2101248);
    uint32_t* Hb1   = (uint32_t*)(w + 4198400);
    uint32_t* flags = (uint32_t*)(w + 6295552);

    prep_kernel<<<1024, NTHR, 0, stream>>>(x, W_hh, b_ih, b_hh, Wh, Wl, bias, xT, Hb0, flags);
    rnn_kernel<<<NBLK, NTHR, 0, stream>>>(xT, W_ih, b_fc, W_fc, Wh, Wl, bias, Hb0, Hb1, flags, out);
}

// Round 8
// 1000.040 us; speedup vs baseline: 2.8781x; 1.0303x over previous
//
#include <hip/hip_runtime.h>
#include <stdint.h>

#define H 512
#define B_SZ 1024
#define T_WARM 256
#define NSTEPS 64
#define TOTAL_T (T_WARM + NSTEPS)

#define RPB 16          // rows per team
#define HC 128          // cols per block
#define NTEAM 64        // B_SZ / RPB
#define NCG 4           // H / HC
#define NBLK 256        // NTEAM * NCG == CU count, 1 block/CU
#define NTHR 512        // 8 waves
#define HSTR 520        // padded LDS k-stride (ushorts)

typedef __attribute__((ext_vector_type(8))) short bf16x8;
typedef __attribute__((ext_vector_type(4))) float f32x4;

__device__ __forceinline__ ushort f2bf(float f) {
    uint32_t u = __builtin_bit_cast(uint32_t, f);
    u += 0x7FFFu + ((u >> 16) & 1u);
    return (ushort)(u >> 16);
}
__device__ __forceinline__ float bf2f(ushort h) {
    uint32_t u = ((uint32_t)h) << 16;
    return __builtin_bit_cast(float, u);
}

__global__ void prep_kernel(const float* __restrict__ x,
                            const float* __restrict__ W_hh,
                            const float* __restrict__ b_ih,
                            const float* __restrict__ b_hh,
                            ushort* __restrict__ Wh, ushort* __restrict__ Wl,
                            float* __restrict__ bias, float* __restrict__ xT,
                            uint32_t* __restrict__ Hb0, uint32_t* __restrict__ flags) {
    int i = blockIdx.x * NTHR + threadIdx.x;     // [0, 524288)
    Hb0[i] = 0u;                                  // h(0) = 0
    if (i < 4096) flags[i] = 0u;                  // flag region (16 KB)
    if (i < H * H) {
        float w = W_hh[i];
        ushort hi = f2bf(w);
        float rem = w - bf2f(hi);
        Wh[i] = hi;
        Wl[i] = f2bf(rem);
    }
    if (i < B_SZ * T_WARM) {
        int b = i & (B_SZ - 1), t = i >> 10;
        xT[t * B_SZ + b] = x[b * T_WARM + t];
    }
    if (i < H) bias[i] = b_ih[i] + b_hh[i];
}

__global__ __launch_bounds__(NTHR, 1)
void rnn_kernel(const float* __restrict__ xT,
                const float* __restrict__ W_ih,
                const float* __restrict__ b_fc_p,
                const float* __restrict__ W_fc,
                const ushort* __restrict__ Wh_g,
                const ushort* __restrict__ Wl_g,
                const float* __restrict__ bias_g,
                uint32_t* __restrict__ Hb0, uint32_t* __restrict__ Hb1,
                uint32_t* __restrict__ flags,
                float* __restrict__ out) {
    __shared__ ushort h_hi[2][RPB * HSTR];   // ping-pong, 2 x 16640 B
    __shared__ ushort h_lo[2][RPB * HSTR];   // ping-pong, 2 x 16640 B
    __shared__ uint32_t tr[RPB * HC];        // self-slice scratch (packed hi|lo), 8192 B
    __shared__ float w_fc_s[H];
    __shared__ float w_in_s[HC];
    __shared__ float bias_s[HC];
    __shared__ float sx[RPB];
    __shared__ float sy[RPB];

    const int tid = threadIdx.x;
    const int bid = blockIdx.x;
    const int team = bid & (NTEAM - 1);    // blocks {team, +64, +128, +192} share bid%8 (XCD)
    const int cg = bid >> 6;               // 0..3
    const int row0 = team * RPB;
    const int col0 = cg * HC;

    w_fc_s[tid & (H - 1)] = W_fc[tid & (H - 1)];
    if (tid < HC) { w_in_s[tid] = W_ih[col0 + tid]; bias_s[tid] = bias_g[col0 + tid]; }
    const float bfc = b_fc_p[0];

    const int lane = tid & 63;
    const int wv = tid >> 6;               // 0..7 = col-tile within block, also k-slice id
    const int n = lane & 15, q = lane >> 4;

    // ---- weights register-resident for all 320 steps: 128 regs/thread ----
    // wave wv owns cols [col0 + wv*16, +16), full K=512
    bf16x8 Bh[16], Bl[16];
    {
        const ushort* wh = Wh_g + (col0 + wv * 16 + n) * H + q * 8;
        const ushort* wl = Wl_g + (col0 + wv * 16 + n) * H + q * 8;
        #pragma unroll
        for (int kt = 0; kt < 16; ++kt) {
            Bh[kt] = *(const bf16x8*)(wh + kt * 32);
            Bl[kt] = *(const bf16x8*)(wl + kt * 32);
        }
    }

    // block flag: producer (team, cg) -> flags[(team*4+cg)*16], 64B stride
    uint32_t* myflag = flags + (team * NCG + cg) * 16;
    // wave wv stages k-slice [wv*64, +64), produced by block (team, wv>>1)
    const uint32_t* pollflag = flags + (team * NCG + (wv >> 1)) * 16;
    const bool selfw = ((wv >> 1) == cg);  // this wave's slice is produced by own block

    for (int t = 0; t < TOTAL_T; ++t) {
        // x for this step -> register, issued before any waiting
        float xv = 0.f;
        if (t < T_WARM && tid < RPB) xv = xT[t * B_SZ + row0 + tid];

        // ---- acquire this wave's k-slice: self -> LDS scratch, remote -> poll + global ----
        uint64_t tmp[8];
        if (t > 0 && selfw) {
            #pragma unroll
            for (int it = 0; it < 8; ++it) {
                int idx = it * 64 + lane;          // r = idx>>5, cpair = idx&31
                int r = idx >> 5, cpair = idx & 31;
                int kloc = (wv & 1) * 64 + cpair * 2;   // local col within block [0,128)
                const uint32_t* p = &tr[r * HC + kloc];
                tmp[it] = (uint64_t)p[0] | ((uint64_t)p[1] << 32);
            }
        } else {
            if (t > 0) {
                while (__hip_atomic_load(pollflag, __ATOMIC_RELAXED, __HIP_MEMORY_SCOPE_AGENT)
                       < (uint32_t)t)
                    __builtin_amdgcn_s_sleep(1);
            }
            const uint32_t* hb = (t & 1) ? Hb1 : Hb0;
            const uint64_t* src = (const uint64_t*)hb;
            #pragma unroll
            for (int it = 0; it < 8; ++it) {
                int idx = it * 64 + lane;          // [0,512): r = idx>>5, cpair = idx&31
                int r = idx >> 5, cpair = idx & 31;
                tmp[it] = __hip_atomic_load(src + ((row0 + r) * 256 + wv * 32 + cpair),
                                            __ATOMIC_RELAXED, __HIP_MEMORY_SCOPE_AGENT);
            }
        }

        // ---- unpack + LDS fill (own slice) into buf (t&1); no pre-barrier (ping-pong) ----
        ushort* hhb = h_hi[t & 1];
        ushort* hlb = h_lo[t & 1];
        #pragma unroll
        for (int it = 0; it < 8; ++it) {
            int idx = it * 64 + lane;
            int r = idx >> 5, cpair = idx & 31;
            int k = wv * 64 + cpair * 2;
            uint64_t u = tmp[it];
            uint32_t w0 = (uint32_t)u, w1 = (uint32_t)(u >> 32);
            uint32_t hw = (w0 >> 16) | (w1 & 0xFFFF0000u);
            uint32_t lw = (w0 & 0xFFFFu) | (w1 << 16);
            *(uint32_t*)(&hhb[r * HSTR + k]) = hw;
            *(uint32_t*)(&hlb[r * HSTR + k]) = lw;
        }
        if (t < T_WARM && tid < RPB) sx[tid] = xv;
        __syncthreads();   // E: all slices staged (also orders tr reads vs epilogue rewrite)

        // ---- rollout: y = h . w_fc + b_fc (redundant per cg; cg0 writes out) ----
        if (t >= T_WARM) {
            if (tid < RPB * 16) {
                int r = tid >> 4, seg = tid & 15;
                const ushort* hh = &hhb[r * HSTR];
                const ushort* hl = &hlb[r * HSTR];
                float s = 0.f;
                #pragma unroll
                for (int kk = 0; kk < 32; ++kk) {
                    int k = seg + kk * 16;
                    s += (bf2f(hh[k]) + bf2f(hl[k])) * w_fc_s[k];
                }
                #pragma unroll
                for (int off = 8; off; off >>= 1) s += __shfl_down(s, off, 16);
                if (seg == 0) {
                    float y = s + bfc;
                    sy[r] = y;
                    if (cg == 0) out[(row0 + r) * NSTEPS + (t - T_WARM)] = y;
                }
            }
            __syncthreads();
        }

        // ---- MFMA: A(16 rows x 512) @ B(512 x 16 cols), 16 kt x 3 terms ----
        f32x4 acc0 = {0.f, 0.f, 0.f, 0.f}, acc1 = {0.f, 0.f, 0.f, 0.f};
        const ushort* ha = &hhb[n * HSTR] + q * 8;    // A row = n
        const ushort* la = &hlb[n * HSTR] + q * 8;
        #pragma unroll
        for (int kt = 0; kt < 16; kt += 2) {
            {
                bf16x8 ah = *(const bf16x8*)(ha + kt * 32);
                bf16x8 al = *(const bf16x8*)(la + kt * 32);
                acc0 = __builtin_amdgcn_mfma_f32_16x16x32_bf16(ah, Bh[kt], acc0, 0, 0, 0);
                acc0 = __builtin_amdgcn_mfma_f32_16x16x32_bf16(al, Bh[kt], acc0, 0, 0, 0);
                acc0 = __builtin_amdgcn_mfma_f32_16x16x32_bf16(ah, Bl[kt], acc0, 0, 0, 0);
            }
            {
                bf16x8 ah = *(const bf16x8*)(ha + (kt + 1) * 32);
                bf16x8 al = *(const bf16x8*)(la + (kt + 1) * 32);
                acc1 = __builtin_amdgcn_mfma_f32_16x16x32_bf16(ah, Bh[kt + 1], acc1, 0, 0, 0);
                acc1 = __builtin_amdgcn_mfma_f32_16x16x32_bf16(al, Bh[kt + 1], acc1, 0, 0, 0);
                acc1 = __builtin_amdgcn_mfma_f32_16x16x32_bf16(ah, Bl[kt + 1], acc1, 0, 0, 0);
            }
        }

        // ---- epilogue: v = acc + s*w_in + bias, relu, pack hi|lo, publish ----
        const int jl = wv * 16 + n;                    // col within block
        const float wi = w_in_s[jl], bj = bias_s[jl];
        uint32_t* dst = ((t & 1) ? Hb0 : Hb1) + col0 + jl;
        #pragma unroll
        for (int i = 0; i < 4; ++i) {
            int m = q * 4 + i;                         // C/D: row = quad*4+reg, col = lane&15
            float sv = (t < T_WARM) ? sx[m] : sy[m];
            float v = acc0[i] + acc1[i] + sv * wi + bj;
            v = fmaxf(v, 0.f);
            ushort hi = f2bf(v);
            float rem = v - bf2f(hi);
            uint32_t u = ((uint32_t)hi << 16) | (uint32_t)f2bf(rem);
            tr[m * HC + jl] = u;                       // self-slice scratch for next step
            __hip_atomic_store(dst + (row0 + m) * H, u, __ATOMIC_RELAXED, __HIP_MEMORY_SCOPE_AGENT);
        }
        __syncthreads();   // I: drains all waves' vmem (vmcnt0) + LDS before flag publish
        if (tid == 0)
            __hip_atomic_store(myflag, (uint32_t)(t + 1), __ATOMIC_RELAXED, __HIP_MEMORY_SCOPE_AGENT);
    }
}

extern "C" void kernel_launch(void* const* d_in, const int* in_sizes, int n_in,
                              void* d_out, int out_size, void* d_ws, size_t ws_size,
                              hipStream_t stream) {
    const float* x    = (const float*)d_in[0];
    const float* W_ih = (const float*)d_in[1];
    const float* W_hh = (const float*)d_in[2];
    const float* b_ih = (const float*)d_in[3];
    const float* b_hh = (const float*)d_in[4];
    const float* W_fc = (const float*)d_in[5];
    const float* b_fc = (const float*)d_in[6];
    float* out = (float*)d_out;

    // ws carve (bytes): Wh 512K | Wl 512K | bias 4K | xT 1M | Hb0 2M | Hb1 2M | flags 16K
    uint8_t* w = (uint8_t*)d_ws;
    ushort*   Wh    = (ushort*)(w);
    ushort*   Wl    = (ushort*)(w + 524288);
    float*    bias  = (float*)(w + 1048576);
    float*    xT    = (float*)(w + 1052672);
    uint32_t* Hb0   = (uint32_t*)(w + 2101248);
    uint32_t* Hb1   = (uint32_t*)(w + 4198400);
    uint32_t* flags = (uint32_t*)(w + 6295552);

    prep_kernel<<<1024, NTHR, 0, stream>>>(x, W_hh, b_ih, b_hh, Wh, Wl, bias, xT, Hb0, flags);
    rnn_kernel<<<NBLK, NTHR, 0, stream>>>(xT, W_ih, b_fc, W_fc, Wh, Wl, bias, Hb0, Hb1, flags, out);
}